// Round 7
// baseline (1627.543 us; speedup 1.0000x reference)
//
#include <hip/hip_runtime.h>
#include <cstdint>
#include <type_traits>

#define B_WIN 4096
#define NTOK 49
#define DIMC 512
#define HEADS 16
#define HD 32
#define M_ROWS (B_WIN * NTOK)          // 200704 = 784*256
#define SCALE 0.17677669529663689f

using bf16x8 = __attribute__((ext_vector_type(8))) short;
using f32x4  = __attribute__((ext_vector_type(4))) float;
using u16x8  = __attribute__((ext_vector_type(8))) unsigned short;

__device__ inline unsigned short f2bf(float f) {
    uint32_t u = __float_as_uint(f);
    uint32_t r = (u + 0x7fffu + ((u >> 16) & 1u)) >> 16;   // RNE
    return (unsigned short)r;
}
__device__ inline unsigned int pk2(float lo, float hi) {
    return (unsigned int)f2bf(lo) | ((unsigned int)f2bf(hi) << 16);
}

__device__ __forceinline__ void gll16(const unsigned short* g, unsigned short* l) {
    __builtin_amdgcn_global_load_lds(
        (const __attribute__((address_space(1))) void*)g,
        (__attribute__((address_space(3))) void*)l, 16, 0, 0);
}

#define DSR(dst, addr) asm volatile("ds_read_b128 %0, %1" : "=v"(dst) : "v"(addr))
#define SCHED0() __builtin_amdgcn_sched_barrier(0)
#define BARRIER() do { SCHED0(); __builtin_amdgcn_s_barrier(); SCHED0(); } while (0)
#define LGKM0() do { asm volatile("s_waitcnt lgkmcnt(0)"); SCHED0(); } while (0)
#define VMCNT(n) do { asm volatile("s_waitcnt vmcnt(" #n ")"); SCHED0(); } while (0)

// ---------------------------------------------------------------------
// f32 -> bf16 conversion
// ---------------------------------------------------------------------
__global__ __launch_bounds__(256) void cvt_f32_bf16(
    const float* __restrict__ in, unsigned short* __restrict__ out, int n4)
{
    for (int i = blockIdx.x * blockDim.x + threadIdx.x; i < n4;
         i += gridDim.x * blockDim.x) {
        float4 v = reinterpret_cast<const float4*>(in)[i];
        ushort4 o;
        o.x = f2bf(v.x); o.y = f2bf(v.y); o.z = f2bf(v.z); o.w = f2bf(v.w);
        reinterpret_cast<ushort4*>(out)[i] = o;
    }
}

// ---------------------------------------------------------------------
// Padded bias table biasPad[h][64][64]: -1e30 outside 49x49.
// ---------------------------------------------------------------------
__global__ __launch_bounds__(256) void build_bias(
    const float* __restrict__ btab, const int* __restrict__ ridx,
    float* __restrict__ biasPad)
{
    const int idx = blockIdx.x * 256 + threadIdx.x;      // 65536
    const int h = idx >> 12, rem = idx & 4095;
    const int i = rem >> 6, j = rem & 63;
    float v = -1e30f;
    if (i < NTOK && j < NTOK) v = btab[ridx[i * NTOK + j] * HEADS + h];
    biasPad[idx] = v;
}

// ---------------------------------------------------------------------
// 8-phase 256-row MFMA GEMM, K=512, NPASS n-tiles of 256 cols per block
// (pipeline stays filled across the n-tile seam; A re-staged from L2).
// Round-5 proven schedule; bias preloaded to regs; mid-loop epilogue.
// ---------------------------------------------------------------------
template <int NPASS, int OUTF32>
__global__ __launch_bounds__(512, 2) void gemm8p(
    const unsigned short* __restrict__ A,
    const unsigned short* __restrict__ W,
    const float* __restrict__ bias,
    void* __restrict__ Craw,
    int N, int ntn)
{
    extern __shared__ unsigned short lds[];
    constexpr int K = 512;
    constexpr int NTT = 8 * NPASS;                        // total K-tiles

    const int nwg = gridDim.x;
    const int bid = blockIdx.x;
    const int wg = (bid & 7) * (nwg >> 3) + (bid >> 3);   // XCD swizzle (nwg%8==0)
    const int tn = wg % ntn, tm = wg / ntn;
    const size_t m0 = (size_t)tm * 256, n0 = (size_t)tn * (256 * NPASS);

    const int t = threadIdx.x;
    const int lane = t & 63, wid = t >> 6;
    const int wm = wid >> 2, wn = wid & 3;
    const int l15 = lane & 15, l4 = lane >> 4;

    // ---- staging precompute (chunk-swizzled global source, linear LDS dest)
    const unsigned short* pA[2];
    const unsigned short* pB[2];
    int dA[2], dB[2];
#pragma unroll
    for (int u = 0; u < 2; ++u) {
        const int f = t + u * 512, rl = f >> 3, c = f & 7, g = c ^ (rl & 7);
        const int lrA = (rl & 63) + (rl >> 6) * 128;        // A unit0 rows
        const int lrB = ((rl >> 5) << 6) + (rl & 31);       // B unit0 rows
        pA[u] = A + (m0 + lrA) * K + g * 8;
        pB[u] = W + (n0 + lrB) * K + g * 8;
        dA[u] = lrA * 64 + c * 8;                           // elements
        dB[u] = 32768 + lrB * 64 + c * 8;                   // B region base
    }
    // tile T: buffer (T&1); A k-offset (T&7)*64; B adds (T>>3)*256 cols
#define STG_A(h, T) { const int _b = ((T) & 1) * 16384, _kt = ((T) & 7) * 64; \
    gll16(pA[0] + (h) * 64 * K + _kt, lds + _b + dA[0] + (h) * 4096);        \
    gll16(pA[1] + (h) * 64 * K + _kt, lds + _b + dA[1] + (h) * 4096); }
#define STG_B(h, T) { const int _b = ((T) & 1) * 16384;                      \
    const size_t _ko = (size_t)((T) >> 3) * (256 * K) + ((T) & 7) * 64;      \
    gll16(pB[0] + (h) * 32 * K + _ko, lds + _b + dB[0] + (h) * 2048);        \
    gll16(pB[1] + (h) * 32 * K + _ko, lds + _b + dB[1] + (h) * 2048); }

    // ---- ds-read address precompute (byte offsets, swizzled)
    const unsigned lbase = (unsigned)(uintptr_t)lds;
    const unsigned swz = (unsigned)(l15 & 7);
    const unsigned cx0 = ((0u + l4) ^ swz) * 16u;
    const unsigned cx1 = ((4u + l4) ^ swz) * 16u;
    const unsigned arow = (unsigned)(wm * 128 + l15) * 128u;
    const unsigned brow = (unsigned)(wn * 64 + l15) * 128u;

    // ---- bias preload (regs; keeps mid-loop epilogue free of vmem reads)
    float br0[4], br1[4];
#pragma unroll
    for (int n = 0; n < 4; ++n) {
        br0[n] = bias[n0 + wn * 64 + n * 16 + l15];
        br1[n] = (NPASS == 2) ? bias[n0 + 256 + wn * 64 + n * 16 + l15] : 0.0f;
    }

    f32x4 acc[8][4] = {};
    bf16x8 a[4][2], b0[2][2], b1[2][2];

    // epilogue for pass p (literal): store + re-zero acc
#define EPI(p, BR) {                                                         \
    _Pragma("unroll") for (int m = 0; m < 8; ++m) {                          \
        _Pragma("unroll") for (int n = 0; n < 4; ++n) {                      \
            const size_t col = n0 + (p) * 256 + wn * 64 + n * 16 + l15;      \
            _Pragma("unroll") for (int r = 0; r < 4; ++r) {                  \
                const size_t row = m0 + wm * 128 + m * 16 + l4 * 4 + r;      \
                const float v = acc[m][n][r] + BR[n];                        \
                if constexpr (OUTF32) ((float*)Craw)[row * N + col] = v;     \
                else ((unsigned short*)Craw)[row * N + col] = f2bf(v);       \
                acc[m][n][r] = 0.0f; } } } }

    // ---- prologue: tile0 (A0,B0,A1,B1) + tile1 (A0,B0,A1); gate; barrier
    STG_A(0, 0); STG_B(0, 0); STG_A(1, 0); STG_B(1, 0);
    STG_A(0, 1); STG_B(0, 1); STG_A(1, 1);
    VMCNT(6);
    BARRIER();

    for (int S = 0; S < NTT; ++S) {
        const int bs = S & 1;
        const unsigned ab = lbase + (unsigned)bs * 32768u;
        const unsigned bb = lbase + 65536u + (unsigned)bs * 32768u;

        // ---- phase 0: read A-half0 + B-n01; stage B1(S+1)
#pragma unroll
        for (int m = 0; m < 4; ++m) {
            DSR(a[m][0], ab + arow + m * 2048u + cx0);
            DSR(a[m][1], ab + arow + m * 2048u + cx1);
        }
#pragma unroll
        for (int n = 0; n < 2; ++n) {
            DSR(b0[n][0], bb + brow + n * 2048u + cx0);
            DSR(b0[n][1], bb + brow + n * 2048u + cx1);
        }
        if (S + 1 < NTT) STG_B(1, S + 1);
        BARRIER(); LGKM0();
        __builtin_amdgcn_s_setprio(1);
#pragma unroll
        for (int m = 0; m < 4; ++m)
#pragma unroll
            for (int n = 0; n < 2; ++n)
#pragma unroll
                for (int ks = 0; ks < 2; ++ks)
                    acc[m][n] = __builtin_amdgcn_mfma_f32_16x16x32_bf16(
                        a[m][ks], b0[n][ks], acc[m][n], 0, 0, 0);
        __builtin_amdgcn_s_setprio(0);
        BARRIER();

        // ---- phase 1: read B-n23; stage A0(S+2)
#pragma unroll
        for (int n = 0; n < 2; ++n) {
            DSR(b1[n][0], bb + brow + (n + 2) * 2048u + cx0);
            DSR(b1[n][1], bb + brow + (n + 2) * 2048u + cx1);
        }
        if (S + 2 < NTT) STG_A(0, S + 2);
        BARRIER(); LGKM0();
        __builtin_amdgcn_s_setprio(1);
#pragma unroll
        for (int m = 0; m < 4; ++m)
#pragma unroll
            for (int n = 0; n < 2; ++n)
#pragma unroll
                for (int ks = 0; ks < 2; ++ks)
                    acc[m][n + 2] = __builtin_amdgcn_mfma_f32_16x16x32_bf16(
                        a[m][ks], b1[n][ks], acc[m][n + 2], 0, 0, 0);
        __builtin_amdgcn_s_setprio(0);
        BARRIER();

        // ---- phase 2: read A-half1; stage B0(S+2)
#pragma unroll
        for (int m = 0; m < 4; ++m) {
            DSR(a[m][0], ab + arow + 8192u + m * 2048u + cx0);
            DSR(a[m][1], ab + arow + 8192u + m * 2048u + cx1);
        }
        if (S + 2 < NTT) STG_B(0, S + 2);
        BARRIER(); LGKM0();
        __builtin_amdgcn_s_setprio(1);
#pragma unroll
        for (int m = 0; m < 4; ++m)
#pragma unroll
            for (int n = 0; n < 2; ++n)
#pragma unroll
                for (int ks = 0; ks < 2; ++ks)
                    acc[m + 4][n] = __builtin_amdgcn_mfma_f32_16x16x32_bf16(
                        a[m][ks], b0[n][ks], acc[m + 4][n], 0, 0, 0);
        __builtin_amdgcn_s_setprio(0);
        BARRIER();

        // ---- phase 3: stage A1(S+2); per-tile counted vmcnt gate
        if (S + 2 < NTT) STG_A(1, S + 2);
        if (S < NTT - 2)       { VMCNT(6); }
        else if (S == NTT - 2) { VMCNT(0); }
        BARRIER();
        __builtin_amdgcn_s_setprio(1);
#pragma unroll
        for (int m = 0; m < 4; ++m)
#pragma unroll
            for (int n = 0; n < 2; ++n)
#pragma unroll
                for (int ks = 0; ks < 2; ++ks)
                    acc[m + 4][n + 2] = __builtin_amdgcn_mfma_f32_16x16x32_bf16(
                        a[m][ks], b1[n][ks], acc[m + 4][n + 2], 0, 0, 0);
        __builtin_amdgcn_s_setprio(0);
        BARRIER();

        // ---- n-tile seam / end: epilogue for the finished pass
        if ((S & 7) == 7) {
            if ((S >> 3) == 0) { EPI(0, br0); }
            else               { EPI(1, br1); }
        }
    }
#undef STG_A
#undef STG_B
#undef EPI
}

// ---------------------------------------------------------------------
// MFMA window attention (round-4/5 proven): one wave per (window, head).
// ---------------------------------------------------------------------
__global__ __launch_bounds__(256) void attn_mfma(
    const unsigned short* __restrict__ qkv,   // [M][1536] bf16
    const float* __restrict__ biasPad,        // [16][64][64] f32
    unsigned short* __restrict__ attn_out)    // [M][512] bf16
{
    __shared__ unsigned short vtile[4][32][72];   // [wave][d][tok+pad]

    const int w = threadIdx.x >> 6;
    const int g = blockIdx.x * 4 + w;
    const int b = g >> 4, h = g & 15;
    const int lane = threadIdx.x & 63;
    const int l15 = lane & 15, l4 = lane >> 4;

    bf16x8 aq[4], bk[4], vload[4];
#pragma unroll
    for (int mt = 0; mt < 4; ++mt) {
        const int tok = mt * 16 + l15;
        bf16x8 zq = {}, zk = {}, zv = {};
        if (tok < NTOK) {
            const unsigned short* base =
                qkv + (size_t)(b * NTOK + tok) * 1536 + h * HD + l4 * 8;
            zq = *(const bf16x8*)base;
            zk = *(const bf16x8*)(base + 512);
            zv = *(const bf16x8*)(base + 1024);
        }
        aq[mt] = zq; bk[mt] = zk; vload[mt] = zv;
    }

#pragma unroll
    for (int mt = 0; mt < 4; ++mt) {
        const int tok = mt * 16 + l15;
#pragma unroll
        for (int e = 0; e < 8; ++e)
            vtile[w][l4 * 8 + e][tok] = (unsigned short)vload[mt][e];
    }

    f32x4 sacc[4][4] = {};
#pragma unroll
    for (int nt = 0; nt < 4; ++nt)
#pragma unroll
        for (int mt = 0; mt < 4; ++mt)
            sacc[nt][mt] = __builtin_amdgcn_mfma_f32_16x16x32_bf16(
                bk[nt], aq[mt], sacc[nt][mt], 0, 0, 0);

    const float* bb = biasPad + (h << 12);
    unsigned int pw[4][4][2];
#pragma unroll
    for (int mt = 0; mt < 4; ++mt) {
        const int i = mt * 16 + l15;
        const float* brow = bb + i * 64 + l4 * 4;
        float mx = -3.0e38f;
#pragma unroll
        for (int nt = 0; nt < 4; ++nt) {
            const float4 b4 = *(const float4*)(brow + nt * 16);
            const float v0 = fmaf(sacc[nt][mt][0], SCALE, b4.x);
            const float v1 = fmaf(sacc[nt][mt][1], SCALE, b4.y);
            const float v2 = fmaf(sacc[nt][mt][2], SCALE, b4.z);
            const float v3 = fmaf(sacc[nt][mt][3], SCALE, b4.w);
            sacc[nt][mt][0] = v0; sacc[nt][mt][1] = v1;
            sacc[nt][mt][2] = v2; sacc[nt][mt][3] = v3;
            mx = fmaxf(mx, fmaxf(fmaxf(v0, v1), fmaxf(v2, v3)));
        }
        mx = fmaxf(mx, __shfl_xor(mx, 16));
        mx = fmaxf(mx, __shfl_xor(mx, 32));
        float sum = 0.f;
#pragma unroll
        for (int nt = 0; nt < 4; ++nt) {
            const float e0 = __expf(sacc[nt][mt][0] - mx);
            const float e1 = __expf(sacc[nt][mt][1] - mx);
            const float e2 = __expf(sacc[nt][mt][2] - mx);
            const float e3 = __expf(sacc[nt][mt][3] - mx);
            sacc[nt][mt][0] = e0; sacc[nt][mt][1] = e1;
            sacc[nt][mt][2] = e2; sacc[nt][mt][3] = e3;
            sum += (e0 + e1) + (e2 + e3);
        }
        sum += __shfl_xor(sum, 16);
        sum += __shfl_xor(sum, 32);
        const float inv = 1.0f / sum;
#pragma unroll
        for (int nt = 0; nt < 4; ++nt) {
            pw[mt][nt][0] = pk2(sacc[nt][mt][0] * inv, sacc[nt][mt][1] * inv);
            pw[mt][nt][1] = pk2(sacc[nt][mt][2] * inv, sacc[nt][mt][3] * inv);
        }
    }

    bf16x8 ap[4][2];
#pragma unroll
    for (int mt = 0; mt < 4; ++mt)
#pragma unroll
        for (int ks = 0; ks < 2; ++ks) {
            union { int wv[4]; bf16x8 v; } u;
#pragma unroll
            for (int q = 0; q < 4; ++q) {
                const int src = l15 + ((2 * (l4 & 1) + (q >> 1)) << 4);
                const int va = __shfl((int)pw[mt][2 * ks][q & 1], src);
                const int vb = __shfl((int)pw[mt][2 * ks + 1][q & 1], src);
                u.wv[q] = (l4 & 2) ? vb : va;
            }
            ap[mt][ks] = u.v;
        }

    bf16x8 bv2[2][2];
#pragma unroll
    for (int n = 0; n < 2; ++n)
#pragma unroll
        for (int ks = 0; ks < 2; ++ks)
            bv2[n][ks] = *(const bf16x8*)&vtile[w][n * 16 + l15][ks * 32 + l4 * 8];

    f32x4 oacc[4][2] = {};
#pragma unroll
    for (int mt = 0; mt < 4; ++mt)
#pragma unroll
        for (int n = 0; n < 2; ++n)
#pragma unroll
            for (int ks = 0; ks < 2; ++ks)
                oacc[mt][n] = __builtin_amdgcn_mfma_f32_16x16x32_bf16(
                    ap[mt][ks], bv2[n][ks], oacc[mt][n], 0, 0, 0);

#pragma unroll
    for (int mt = 0; mt < 4; ++mt) {
#pragma unroll
        for (int r = 0; r < 4; ++r) {
            const int i = mt * 16 + l4 * 4 + r;
            if (i < NTOK) {
                unsigned short* op =
                    attn_out + (size_t)(b * NTOK + i) * DIMC + h * HD + l15;
                op[0]  = f2bf(oacc[mt][0][r]);
                op[16] = f2bf(oacc[mt][1][r]);
            }
        }
    }
}

extern "C" void kernel_launch(void* const* d_in, const int* in_sizes, int n_in,
                              void* d_out, int out_size, void* d_ws, size_t ws_size,
                              hipStream_t stream)
{
    const float* x      = (const float*)d_in[0];
    const float* qkv_w  = (const float*)d_in[1];
    const float* qkv_b  = (const float*)d_in[2];
    const float* proj_w = (const float*)d_in[3];
    const float* proj_b = (const float*)d_in[4];
    const float* btab   = (const float*)d_in[5];
    const int*   ridx   = (const int*)d_in[6];
    float* out = (float*)d_out;

    // workspace (~1.03 GB; ws >= 1.64 GB proven round 1)
    char* w = (char*)d_ws;
    const size_t SZ_XBF   = (size_t)M_ROWS * DIMC * 2;        // 205,520,896
    const size_t SZ_QKVW  = (size_t)1536 * 512 * 2;
    const size_t SZ_PROJW = (size_t)512 * 512 * 2;
    const size_t SZ_BIAS  = (size_t)HEADS * 64 * 64 * 4;
    const size_t SZ_QKV   = (size_t)M_ROWS * 1536 * 2;        // 616,562,688
    unsigned short* x_bf     = (unsigned short*)w;
    unsigned short* qkvw_bf  = (unsigned short*)(w + SZ_XBF);
    unsigned short* projw_bf = (unsigned short*)(w + SZ_XBF + SZ_QKVW);
    float*          biasPad  = (float*)(w + SZ_XBF + SZ_QKVW + SZ_PROJW);
    unsigned short* qkv      = (unsigned short*)(w + SZ_XBF + SZ_QKVW + SZ_PROJW + SZ_BIAS);
    unsigned short* attn_out = (unsigned short*)((char*)qkv + SZ_QKV);

    hipFuncSetAttribute(reinterpret_cast<const void*>(&gemm8p<2, 0>),
                        hipFuncAttributeMaxDynamicSharedMemorySize, 131072);
    hipFuncSetAttribute(reinterpret_cast<const void*>(&gemm8p<2, 1>),
                        hipFuncAttributeMaxDynamicSharedMemorySize, 131072);

    cvt_f32_bf16<<<2048, 256, 0, stream>>>(x, x_bf, M_ROWS * DIMC / 4);
    cvt_f32_bf16<<<128, 256, 0, stream>>>(qkv_w, qkvw_bf, 1536 * 512 / 4);
    cvt_f32_bf16<<<64, 256, 0, stream>>>(proj_w, projw_bf, 512 * 512 / 4);
    build_bias<<<256, 256, 0, stream>>>(btab, ridx, biasPad);

    // qkv: 784 m-tiles x 3 n-supertiles (2 passes each) = 2352 blocks (div 8)
    gemm8p<2, 0><<<2352, 512, 131072, stream>>>(
        x_bf, qkvw_bf, qkv_b, qkv, 1536, 3);

    attn_mfma<<<16384, 256, 0, stream>>>(qkv, biasPad, attn_out);

    // proj: 784 m-tiles x 1 n-supertile (2 passes) = 784 blocks (div 8)
    gemm8p<2, 1><<<784, 512, 131072, stream>>>(
        attn_out, projw_bf, proj_b, out, 512, 1);
}

// Round 8
// 942.092 us; speedup vs baseline: 1.7276x; 1.7276x over previous
//
#include <hip/hip_runtime.h>
#include <cstdint>
#include <type_traits>

#define B_WIN 4096
#define NTOK 49
#define DIMC 512
#define HEADS 16
#define HD 32
#define M_ROWS (B_WIN * NTOK)          // 200704 = 784*256
#define SCALE 0.17677669529663689f

using bf16x8 = __attribute__((ext_vector_type(8))) short;
using f32x4  = __attribute__((ext_vector_type(4))) float;
using u16x8  = __attribute__((ext_vector_type(8))) unsigned short;

__device__ inline unsigned short f2bf(float f) {
    uint32_t u = __float_as_uint(f);
    uint32_t r = (u + 0x7fffu + ((u >> 16) & 1u)) >> 16;   // RNE
    return (unsigned short)r;
}
__device__ inline unsigned int pk2(float lo, float hi) {
    return (unsigned int)f2bf(lo) | ((unsigned int)f2bf(hi) << 16);
}

__device__ __forceinline__ void gll16(const unsigned short* g, unsigned short* l) {
    __builtin_amdgcn_global_load_lds(
        (const __attribute__((address_space(1))) void*)g,
        (__attribute__((address_space(3))) void*)l, 16, 0, 0);
}

#define DSR(dst, addr) asm volatile("ds_read_b128 %0, %1" : "=v"(dst) : "v"(addr))
#define SCHED0() __builtin_amdgcn_sched_barrier(0)
#define BARRIER() do { SCHED0(); __builtin_amdgcn_s_barrier(); SCHED0(); } while (0)
#define LGKM0() do { asm volatile("s_waitcnt lgkmcnt(0)"); SCHED0(); } while (0)

// ---------------------------------------------------------------------
// f32 -> bf16 conversion (x and weights)
// ---------------------------------------------------------------------
__global__ __launch_bounds__(256) void cvt_f32_bf16(
    const float* __restrict__ in, unsigned short* __restrict__ out, int n4)
{
    for (int i = blockIdx.x * blockDim.x + threadIdx.x; i < n4;
         i += gridDim.x * blockDim.x) {
        float4 v = reinterpret_cast<const float4*>(in)[i];
        ushort4 o;
        o.x = f2bf(v.x); o.y = f2bf(v.y); o.z = f2bf(v.z); o.w = f2bf(v.w);
        reinterpret_cast<ushort4*>(out)[i] = o;
    }
}

// ---------------------------------------------------------------------
// Padded bias table biasPad[h][64][64]: -1e30 outside 49x49.
// ---------------------------------------------------------------------
__global__ __launch_bounds__(256) void build_bias(
    const float* __restrict__ btab, const int* __restrict__ ridx,
    float* __restrict__ biasPad)
{
    const int idx = blockIdx.x * 256 + threadIdx.x;      // 65536
    const int h = idx >> 12, rem = idx & 4095;
    const int i = rem >> 6, j = rem & 63;
    float v = -1e30f;
    if (i < NTOK && j < NTOK) v = btab[ridx[i * NTOK + j] * HEADS + h];
    biasPad[idx] = v;
}

// ---------------------------------------------------------------------
// 8-phase 256x256 bf16 MFMA GEMM (round-5 proven: 939 us system).
// K=512 fixed (NT=8 K-tiles of 64). 512 thr, 8 waves (2Mx4N), BK=64,
// 2 LDS dbuf (128 KiB dynamic), counted vmcnt(6), XOR chunk swizzle.
// Region-liveness (verified R5): STG_X(h,T) writes exactly the rows that
// phase h's DSRs read, issued only after that phase's barrier.
// NOTE (R7 lesson): no stores inside the counted-vmcnt loop, ever.
// ---------------------------------------------------------------------
template <int OUTF32>
__global__ __launch_bounds__(512, 2) void gemm8p(
    const unsigned short* __restrict__ A,
    const unsigned short* __restrict__ W,
    const float* __restrict__ bias,
    void* __restrict__ Craw,
    int N, int ntn)
{
    extern __shared__ unsigned short lds[];
    constexpr int K = 512, NT = 8;

    const int nwg = gridDim.x;
    const int bid = blockIdx.x;
    const int wg = (bid & 7) * (nwg >> 3) + (bid >> 3);   // XCD swizzle (nwg%8==0)
    const int tn = wg % ntn, tm = wg / ntn;
    const size_t m0 = (size_t)tm * 256, n0 = (size_t)tn * 256;

    const int t = threadIdx.x;
    const int lane = t & 63, wid = t >> 6;
    const int wm = wid >> 2, wn = wid & 3;
    const int l15 = lane & 15, l4 = lane >> 4;

    // ---- staging precompute (chunk-swizzled global source, linear LDS dest)
    const unsigned short* pA[2];
    const unsigned short* pB[2];
    int dA[2], dB[2];
#pragma unroll
    for (int u = 0; u < 2; ++u) {
        const int f = t + u * 512, rl = f >> 3, c = f & 7, g = c ^ (rl & 7);
        const int lrA = (rl & 63) + (rl >> 6) * 128;        // A unit0 rows
        const int lrB = ((rl >> 5) << 6) + (rl & 31);       // B unit0 rows
        pA[u] = A + (m0 + lrA) * K + g * 8;
        pB[u] = W + (n0 + lrB) * K + g * 8;
        dA[u] = lrA * 64 + c * 8;                           // elements
        dB[u] = 32768 + lrB * 64 + c * 8;                   // B region base
    }
#define STG_A(h, T) { const int _b = ((T) & 1) * 16384, _kt = (T) * 64;      \
    gll16(pA[0] + (h) * 64 * K + _kt, lds + _b + dA[0] + (h) * 4096);        \
    gll16(pA[1] + (h) * 64 * K + _kt, lds + _b + dA[1] + (h) * 4096); }
#define STG_B(h, T) { const int _b = ((T) & 1) * 16384, _kt = (T) * 64;      \
    gll16(pB[0] + (h) * 32 * K + _kt, lds + _b + dB[0] + (h) * 2048);        \
    gll16(pB[1] + (h) * 32 * K + _kt, lds + _b + dB[1] + (h) * 2048); }

    // ---- ds-read address precompute (byte offsets, swizzled)
    const unsigned lbase = (unsigned)(uintptr_t)lds;
    const unsigned swz = (unsigned)(l15 & 7);
    const unsigned cx0 = ((0u + l4) ^ swz) * 16u;
    const unsigned cx1 = ((4u + l4) ^ swz) * 16u;
    const unsigned arow = (unsigned)(wm * 128 + l15) * 128u;
    const unsigned brow = (unsigned)(wn * 64 + l15) * 128u;

    f32x4 acc[8][4] = {};
    bf16x8 a[4][2], b0[2][2], b1[2][2];

    // ---- prologue: tile0 (A0,B0,A1,B1) + tile1 (A0,B0,A1); gate; barrier
    STG_A(0, 0); STG_B(0, 0); STG_A(1, 0); STG_B(1, 0);
    STG_A(0, 1); STG_B(0, 1); STG_A(1, 1);
    asm volatile("s_waitcnt vmcnt(6)");
    SCHED0();
    BARRIER();

    for (int S = 0; S < NT; ++S) {
        const int bs = S & 1;
        const unsigned ab = lbase + (unsigned)bs * 32768u;
        const unsigned bb = lbase + 65536u + (unsigned)bs * 32768u;

        // ---- phase 0: read A-half0 + B-n01; stage B1(S+1)
#pragma unroll
        for (int m = 0; m < 4; ++m) {
            DSR(a[m][0], ab + arow + m * 2048u + cx0);
            DSR(a[m][1], ab + arow + m * 2048u + cx1);
        }
#pragma unroll
        for (int n = 0; n < 2; ++n) {
            DSR(b0[n][0], bb + brow + n * 2048u + cx0);
            DSR(b0[n][1], bb + brow + n * 2048u + cx1);
        }
        if (S + 1 < NT) STG_B(1, S + 1);
        BARRIER(); LGKM0();
        __builtin_amdgcn_s_setprio(1);
#pragma unroll
        for (int m = 0; m < 4; ++m)
#pragma unroll
            for (int n = 0; n < 2; ++n)
#pragma unroll
                for (int ks = 0; ks < 2; ++ks)
                    acc[m][n] = __builtin_amdgcn_mfma_f32_16x16x32_bf16(
                        a[m][ks], b0[n][ks], acc[m][n], 0, 0, 0);
        __builtin_amdgcn_s_setprio(0);
        BARRIER();

        // ---- phase 1: read B-n23; stage A0(S+2)
#pragma unroll
        for (int n = 0; n < 2; ++n) {
            DSR(b1[n][0], bb + brow + (n + 2) * 2048u + cx0);
            DSR(b1[n][1], bb + brow + (n + 2) * 2048u + cx1);
        }
        if (S + 2 < NT) STG_A(0, S + 2);
        BARRIER(); LGKM0();
        __builtin_amdgcn_s_setprio(1);
#pragma unroll
        for (int m = 0; m < 4; ++m)
#pragma unroll
            for (int n = 0; n < 2; ++n)
#pragma unroll
                for (int ks = 0; ks < 2; ++ks)
                    acc[m][n + 2] = __builtin_amdgcn_mfma_f32_16x16x32_bf16(
                        a[m][ks], b1[n][ks], acc[m][n + 2], 0, 0, 0);
        __builtin_amdgcn_s_setprio(0);
        BARRIER();

        // ---- phase 2: read A-half1; stage B0(S+2)
#pragma unroll
        for (int m = 0; m < 4; ++m) {
            DSR(a[m][0], ab + arow + 8192u + m * 2048u + cx0);
            DSR(a[m][1], ab + arow + 8192u + m * 2048u + cx1);
        }
        if (S + 2 < NT) STG_B(0, S + 2);
        BARRIER(); LGKM0();
        __builtin_amdgcn_s_setprio(1);
#pragma unroll
        for (int m = 0; m < 4; ++m)
#pragma unroll
            for (int n = 0; n < 2; ++n)
#pragma unroll
                for (int ks = 0; ks < 2; ++ks)
                    acc[m + 4][n] = __builtin_amdgcn_mfma_f32_16x16x32_bf16(
                        a[m][ks], b0[n][ks], acc[m + 4][n], 0, 0, 0);
        __builtin_amdgcn_s_setprio(0);
        BARRIER();

        // ---- phase 3: stage A1(S+2); per-tile counted vmcnt gate
        if (S + 2 < NT) STG_A(1, S + 2);
        if (S < NT - 2)       { asm volatile("s_waitcnt vmcnt(6)"); SCHED0(); }
        else if (S == NT - 2) { asm volatile("s_waitcnt vmcnt(0)"); SCHED0(); }
        BARRIER();
        __builtin_amdgcn_s_setprio(1);
#pragma unroll
        for (int m = 0; m < 4; ++m)
#pragma unroll
            for (int n = 0; n < 2; ++n)
#pragma unroll
                for (int ks = 0; ks < 2; ++ks)
                    acc[m + 4][n + 2] = __builtin_amdgcn_mfma_f32_16x16x32_bf16(
                        a[m][ks], b1[n][ks], acc[m + 4][n + 2], 0, 0, 0);
        __builtin_amdgcn_s_setprio(0);
        BARRIER();
    }

    // ---- epilogue (after the loop only — R7 lesson)
#pragma unroll
    for (int m = 0; m < 8; ++m) {
#pragma unroll
        for (int n = 0; n < 4; ++n) {
            const size_t col = n0 + wn * 64 + n * 16 + l15;
            const float bv = bias[col];
#pragma unroll
            for (int r = 0; r < 4; ++r) {
                const size_t row = m0 + wm * 128 + m * 16 + l4 * 4 + r;
                const float v = acc[m][n][r] + bv;
                if constexpr (OUTF32)
                    ((float*)Craw)[row * N + col] = v;
                else
                    ((unsigned short*)Craw)[row * N + col] = f2bf(v);
            }
        }
    }
#undef STG_A
#undef STG_B
}

// ---------------------------------------------------------------------
// MFMA window attention (round-4/5 proven): one wave per (window, head).
// ---------------------------------------------------------------------
__global__ __launch_bounds__(256) void attn_mfma(
    const unsigned short* __restrict__ qkv,   // [M][1536] bf16
    const float* __restrict__ biasPad,        // [16][64][64] f32
    unsigned short* __restrict__ attn_out)    // [M][512] bf16
{
    __shared__ unsigned short vtile[4][32][72];   // [wave][d][tok+pad]

    const int w = threadIdx.x >> 6;
    const int g = blockIdx.x * 4 + w;
    const int b = g >> 4, h = g & 15;
    const int lane = threadIdx.x & 63;
    const int l15 = lane & 15, l4 = lane >> 4;

    bf16x8 aq[4], bk[4], vload[4];
#pragma unroll
    for (int mt = 0; mt < 4; ++mt) {
        const int tok = mt * 16 + l15;
        bf16x8 zq = {}, zk = {}, zv = {};
        if (tok < NTOK) {
            const unsigned short* base =
                qkv + (size_t)(b * NTOK + tok) * 1536 + h * HD + l4 * 8;
            zq = *(const bf16x8*)base;
            zk = *(const bf16x8*)(base + 512);
            zv = *(const bf16x8*)(base + 1024);
        }
        aq[mt] = zq; bk[mt] = zk; vload[mt] = zv;
    }

#pragma unroll
    for (int mt = 0; mt < 4; ++mt) {
        const int tok = mt * 16 + l15;
#pragma unroll
        for (int e = 0; e < 8; ++e)
            vtile[w][l4 * 8 + e][tok] = (unsigned short)vload[mt][e];
    }

    f32x4 sacc[4][4] = {};
#pragma unroll
    for (int nt = 0; nt < 4; ++nt)
#pragma unroll
        for (int mt = 0; mt < 4; ++mt)
            sacc[nt][mt] = __builtin_amdgcn_mfma_f32_16x16x32_bf16(
                bk[nt], aq[mt], sacc[nt][mt], 0, 0, 0);

    const float* bb = biasPad + (h << 12);
    unsigned int pw[4][4][2];
#pragma unroll
    for (int mt = 0; mt < 4; ++mt) {
        const int i = mt * 16 + l15;
        const float* brow = bb + i * 64 + l4 * 4;
        float mx = -3.0e38f;
#pragma unroll
        for (int nt = 0; nt < 4; ++nt) {
            const float4 b4 = *(const float4*)(brow + nt * 16);
            const float v0 = fmaf(sacc[nt][mt][0], SCALE, b4.x);
            const float v1 = fmaf(sacc[nt][mt][1], SCALE, b4.y);
            const float v2 = fmaf(sacc[nt][mt][2], SCALE, b4.z);
            const float v3 = fmaf(sacc[nt][mt][3], SCALE, b4.w);
            sacc[nt][mt][0] = v0; sacc[nt][mt][1] = v1;
            sacc[nt][mt][2] = v2; sacc[nt][mt][3] = v3;
            mx = fmaxf(mx, fmaxf(fmaxf(v0, v1), fmaxf(v2, v3)));
        }
        mx = fmaxf(mx, __shfl_xor(mx, 16));
        mx = fmaxf(mx, __shfl_xor(mx, 32));
        float sum = 0.f;
#pragma unroll
        for (int nt = 0; nt < 4; ++nt) {
            const float e0 = __expf(sacc[nt][mt][0] - mx);
            const float e1 = __expf(sacc[nt][mt][1] - mx);
            const float e2 = __expf(sacc[nt][mt][2] - mx);
            const float e3 = __expf(sacc[nt][mt][3] - mx);
            sacc[nt][mt][0] = e0; sacc[nt][mt][1] = e1;
            sacc[nt][mt][2] = e2; sacc[nt][mt][3] = e3;
            sum += (e0 + e1) + (e2 + e3);
        }
        sum += __shfl_xor(sum, 16);
        sum += __shfl_xor(sum, 32);
        const float inv = 1.0f / sum;
#pragma unroll
        for (int nt = 0; nt < 4; ++nt) {
            pw[mt][nt][0] = pk2(sacc[nt][mt][0] * inv, sacc[nt][mt][1] * inv);
            pw[mt][nt][1] = pk2(sacc[nt][mt][2] * inv, sacc[nt][mt][3] * inv);
        }
    }

    bf16x8 ap[4][2];
#pragma unroll
    for (int mt = 0; mt < 4; ++mt)
#pragma unroll
        for (int ks = 0; ks < 2; ++ks) {
            union { int wv[4]; bf16x8 v; } u;
#pragma unroll
            for (int q = 0; q < 4; ++q) {
                const int src = l15 + ((2 * (l4 & 1) + (q >> 1)) << 4);
                const int va = __shfl((int)pw[mt][2 * ks][q & 1], src);
                const int vb = __shfl((int)pw[mt][2 * ks + 1][q & 1], src);
                u.wv[q] = (l4 & 2) ? vb : va;
            }
            ap[mt][ks] = u.v;
        }

    bf16x8 bv2[2][2];
#pragma unroll
    for (int n = 0; n < 2; ++n)
#pragma unroll
        for (int ks = 0; ks < 2; ++ks)
            bv2[n][ks] = *(const bf16x8*)&vtile[w][n * 16 + l15][ks * 32 + l4 * 8];

    f32x4 oacc[4][2] = {};
#pragma unroll
    for (int mt = 0; mt < 4; ++mt)
#pragma unroll
        for (int n = 0; n < 2; ++n)
#pragma unroll
            for (int ks = 0; ks < 2; ++ks)
                oacc[mt][n] = __builtin_amdgcn_mfma_f32_16x16x32_bf16(
                    ap[mt][ks], bv2[n][ks], oacc[mt][n], 0, 0, 0);

#pragma unroll
    for (int mt = 0; mt < 4; ++mt) {
#pragma unroll
        for (int r = 0; r < 4; ++r) {
            const int i = mt * 16 + l4 * 4 + r;
            if (i < NTOK) {
                unsigned short* op =
                    attn_out + (size_t)(b * NTOK + i) * DIMC + h * HD + l15;
                op[0]  = f2bf(oacc[mt][0][r]);
                op[16] = f2bf(oacc[mt][1][r]);
            }
        }
    }
}

extern "C" void kernel_launch(void* const* d_in, const int* in_sizes, int n_in,
                              void* d_out, int out_size, void* d_ws, size_t ws_size,
                              hipStream_t stream)
{
    const float* x      = (const float*)d_in[0];
    const float* qkv_w  = (const float*)d_in[1];
    const float* qkv_b  = (const float*)d_in[2];
    const float* proj_w = (const float*)d_in[3];
    const float* proj_b = (const float*)d_in[4];
    const float* btab   = (const float*)d_in[5];
    const int*   ridx   = (const int*)d_in[6];
    float* out = (float*)d_out;

    // workspace (~1.03 GB; ws >= 1.64 GB proven round 1)
    char* w = (char*)d_ws;
    const size_t SZ_XBF   = (size_t)M_ROWS * DIMC * 2;        // 205,520,896
    const size_t SZ_QKVW  = (size_t)1536 * 512 * 2;
    const size_t SZ_PROJW = (size_t)512 * 512 * 2;
    const size_t SZ_BIAS  = (size_t)HEADS * 64 * 64 * 4;
    const size_t SZ_QKV   = (size_t)M_ROWS * 1536 * 2;        // 616,562,688
    unsigned short* x_bf     = (unsigned short*)w;
    unsigned short* qkvw_bf  = (unsigned short*)(w + SZ_XBF);
    unsigned short* projw_bf = (unsigned short*)(w + SZ_XBF + SZ_QKVW);
    float*          biasPad  = (float*)(w + SZ_XBF + SZ_QKVW + SZ_PROJW);
    unsigned short* qkv      = (unsigned short*)(w + SZ_XBF + SZ_QKVW + SZ_PROJW + SZ_BIAS);
    unsigned short* attn_out = (unsigned short*)((char*)qkv + SZ_QKV);

    hipFuncSetAttribute(reinterpret_cast<const void*>(&gemm8p<0>),
                        hipFuncAttributeMaxDynamicSharedMemorySize, 131072);
    hipFuncSetAttribute(reinterpret_cast<const void*>(&gemm8p<1>),
                        hipFuncAttributeMaxDynamicSharedMemorySize, 131072);

    cvt_f32_bf16<<<4096, 256, 0, stream>>>(x, x_bf, M_ROWS * DIMC / 4);
    cvt_f32_bf16<<<128, 256, 0, stream>>>(qkv_w, qkvw_bf, 1536 * 512 / 4);
    cvt_f32_bf16<<<64, 256, 0, stream>>>(proj_w, projw_bf, 512 * 512 / 4);
    build_bias<<<256, 256, 0, stream>>>(btab, ridx, biasPad);

    // qkv: 784 x 6 = 4704 blocks (div 8)
    gemm8p<0><<<4704, 512, 131072, stream>>>(
        x_bf, qkvw_bf, qkv_b, qkv, 1536, 6);

    attn_mfma<<<16384, 256, 0, stream>>>(qkv, biasPad, attn_out);

    // proj: 784 x 2 = 1568 blocks (div 8)
    gemm8p<1><<<1568, 512, 131072, stream>>>(
        attn_out, projw_bf, proj_b, out, 512, 2);
}